// Round 11
// baseline (408.444 us; speedup 1.0000x reference)
//
#include <hip/hip_runtime.h>
#include <hip/hip_bf16.h>
#include <math.h>

#define BB 8
#define SS 2048
#define HH 8
#define DKK 64
#define DM 512

typedef short bf16x8 __attribute__((ext_vector_type(8)));
typedef short bf16x4 __attribute__((ext_vector_type(4)));
typedef float f32x4 __attribute__((ext_vector_type(4)));
#define MFMA16(a, b, c) __builtin_amdgcn_mfma_f32_16x16x32_bf16(a, b, c, 0, 0, 0)

#if __has_builtin(__builtin_amdgcn_exp2f)
#define EXP2(x) __builtin_amdgcn_exp2f(x)
#else
#define EXP2(x) exp2f(x)
#endif

__device__ __forceinline__ unsigned short f2bf(float f) {
    __hip_bfloat16 h = __float2bfloat16(f);
    return *reinterpret_cast<unsigned short*>(&h);
}

__device__ __forceinline__ float max3f(float a, float b, float c) {
    return fmaxf(fmaxf(a, b), c);   // clang fuses to v_max3_f32
}

// Convert 8 consecutive fp32 -> 8 bf16, return as uint4 for a 16B store.
__device__ __forceinline__ uint4 cvt8(const float* __restrict__ src) {
    float4 a = *(const float4*)src;
    float4 b = *(const float4*)(src + 4);
    unsigned short tmp[8];
    tmp[0] = f2bf(a.x); tmp[1] = f2bf(a.y); tmp[2] = f2bf(a.z); tmp[3] = f2bf(a.w);
    tmp[4] = f2bf(b.x); tmp[5] = f2bf(b.y); tmp[6] = f2bf(b.z); tmp[7] = f2bf(b.w);
    return *(uint4*)tmp;
}

// ---------------------------------------------------------------------------
// Prep (one launch, block-range dispatch):
//   [0,16384):     mask int32 [S][S] -> mb uint64 [S][S/64] via __ballot
//   [16384,16768): Wq/Wk/Wv fp32 -> bf16 into wdst (1.5 MB)
//   [16768,20864): Xq fp32 -> bf16 into xqd (16 MiB, vtb segment)
//   [20864,24960): Xv fp32 -> bf16 into xvd (16 MiB, ab segment)
// X conversion moved here from proj staging: proj converted each X panel 4x
// redundantly on its VALU-critical path; here it is BW-bound and done once.
// ---------------------------------------------------------------------------
__global__ __launch_bounds__(256) void prep_kernel(
    const int* __restrict__ mask, unsigned long long* __restrict__ mb,
    const float* __restrict__ Wq, const float* __restrict__ Wk,
    const float* __restrict__ Wv, unsigned short* __restrict__ wdst,
    const float* __restrict__ Xq, const float* __restrict__ Xv,
    unsigned short* __restrict__ xqd, unsigned short* __restrict__ xvd)
{
    const int bid = blockIdx.x;
    const int t = threadIdx.x;
    if (bid < 16384) {
        const int wid = (bid << 2) | (t >> 6);   // global wave id == word idx
        const int lane = t & 63;
        const int q = wid >> 5;                   // / (SS/64)
        const int c = wid & 31;
        int e = mask[(size_t)q * SS + (c << 6) + lane];
        unsigned long long bal = __ballot(e != 0);
        if (lane == 0) mb[wid] = bal;
    } else if (bid < 16768) {
        const int idx = (bid - 16384) * 256 + t;  // 0..98303
        const int which = idx >> 15;              // / 32768
        const int off = (idx & 32767) * 8;
        const float* src = (which == 0) ? Wq : (which == 1) ? Wk : Wv;
        *(uint4*)(wdst + (size_t)which * 262144 + off) = cvt8(src + off);
    } else if (bid < 20864) {
        const size_t off = ((size_t)(bid - 16768) * 256 + t) * 8;
        *(uint4*)(xqd + off) = cvt8(Xq + off);
    } else {
        const size_t off = ((size_t)(bid - 20864) * 256 + t) * 8;
        *(uint4*)(xvd + off) = cvt8(Xv + off);
    }
}

// ---------------------------------------------------------------------------
// QKV projection, mode = mode0 + blockIdx.z:
//   mode 0 (Q): X bf16 (pre-converted, uint4 staging), scatter out, *qscale
//   mode 1 (K): X fp32 (cvt8 staging), scatter out
//   mode 2 (V): X bf16 (pre-converted), out TRANSPOSED to [B*H][64][S]
// W pre-converted bf16 (uint4 staging — round-7 proven form; round-10's
// gll16 W staging was neutral-to-negative, reverted).
// Launched twice: (4,128,1) mode0=0 (Q; reads vtb-as-Xq before V overwrites
// it), then (4,128,2) mode0=1 (K,V — disjoint outputs, safe in one launch).
// ---------------------------------------------------------------------------
__global__ __launch_bounds__(256, 2) void proj_qkv(
    const unsigned short* __restrict__ XqB, const float* __restrict__ XkF,
    const unsigned short* __restrict__ XvB,
    const unsigned short* __restrict__ Wb,
    const float* __restrict__ bq, const float* __restrict__ bk,
    const float* __restrict__ bv,
    unsigned short* __restrict__ qout, unsigned short* __restrict__ kout,
    unsigned short* __restrict__ vtout,
    float qscale, int mode0)
{
    const int mode = mode0 + blockIdx.z;
    const unsigned short* XB = (mode == 0) ? XqB : XvB;
    const float* bias = (mode == 0) ? bq : (mode == 1) ? bk : bv;
    unsigned short* out = (mode == 0) ? qout : (mode == 1) ? kout : vtout;
    const unsigned short* W = Wb + (size_t)mode * 262144;
    const float scale = (mode == 0) ? qscale : 1.0f;

    __shared__ __align__(16) unsigned short Xs[128][72];
    __shared__ __align__(16) unsigned short Ws[128][72];
    const int t = threadIdx.x;
    const int w = t >> 6, l = t & 63;
    const int l15 = l & 15, lg = l >> 4;
    const int n0 = blockIdx.x * 128, m0 = blockIdx.y * 128;
    const int mo = (w & 1) * 64, no = (w >> 1) * 64;

    f32x4 acc[4][4];
#pragma unroll
    for (int i = 0; i < 4; i++)
#pragma unroll
        for (int j = 0; j < 4; j++) acc[i][j] = (f32x4){0.f, 0.f, 0.f, 0.f};

    for (int k0 = 0; k0 < DM; k0 += 64) {
        __syncthreads();
#pragma unroll
        for (int rr = 0; rr < 4; rr++) {
            int idx = rr * 2048 + t * 8;
            int row = idx >> 6, col = idx & 63;
            if (mode == 1)
                *(uint4*)&Xs[row][col] = cvt8(XkF + (size_t)(m0 + row) * DM + k0 + col);
            else
                *(uint4*)&Xs[row][col] = *(const uint4*)(XB + (size_t)(m0 + row) * DM + k0 + col);
            *(uint4*)&Ws[row][col] = *(const uint4*)(W + (size_t)(n0 + row) * DM + k0 + col);
        }
        __syncthreads();

        bf16x8 af[4][2], bfr[4][2];
#pragma unroll
        for (int mt = 0; mt < 4; mt++) {
            af[mt][0] = *(const bf16x8*)&Xs[mo + mt * 16 + l15][lg * 8];
            af[mt][1] = *(const bf16x8*)&Xs[mo + mt * 16 + l15][32 + lg * 8];
        }
#pragma unroll
        for (int nt = 0; nt < 4; nt++) {
            bfr[nt][0] = *(const bf16x8*)&Ws[no + nt * 16 + l15][lg * 8];
            bfr[nt][1] = *(const bf16x8*)&Ws[no + nt * 16 + l15][32 + lg * 8];
        }
#pragma unroll
        for (int mt = 0; mt < 4; mt++)
#pragma unroll
            for (int nt = 0; nt < 4; nt++) {
                acc[mt][nt] = MFMA16(af[mt][0], bfr[nt][0], acc[mt][nt]);
                acc[mt][nt] = MFMA16(af[mt][1], bfr[nt][1], acc[mt][nt]);
            }
    }

    float bv4[4];
#pragma unroll
    for (int nt = 0; nt < 4; nt++) bv4[nt] = bias[n0 + no + nt * 16 + l15];

    const int h = (n0 + no) >> 6;
    if (mode == 2) {
        // transposed V epilogue: vt[bh][d][s]
#pragma unroll
        for (int mt = 0; mt < 4; mt++) {
            int m = m0 + mo + mt * 16 + lg * 4;       // 4-aligned, never crosses b
            int bb = m >> 11, s = m & (SS - 1);
#pragma unroll
            for (int nt = 0; nt < 4; nt++) {
                int d = nt * 16 + l15;
                bf16x4 pk;
#pragma unroll
                for (int r = 0; r < 4; r++) pk[r] = (short)f2bf(acc[mt][nt][r] + bv4[nt]);
                *(bf16x4*)(out + (((size_t)bb * HH + h) * DKK + d) * SS + s) = pk;
            }
        }
    } else {
#pragma unroll
        for (int mt = 0; mt < 4; mt++)
#pragma unroll
            for (int nt = 0; nt < 4; nt++)
#pragma unroll
                for (int r = 0; r < 4; r++) {
                    int m = m0 + mo + mt * 16 + lg * 4 + r;
                    int d = nt * 16 + l15;
                    float v = (acc[mt][nt][r] + bv4[nt]) * scale;
                    int bb = m >> 11, s = m & (SS - 1);
                    out[(((size_t)bb * HH + h) * SS + s) * 64 + d] = f2bf(v);
                }
    }
}

// ---------------------------------------------------------------------------
// Output projection: out[m][n] = sum_k A[m][k]*Wo[n][k] + bo[n]
// A bf16 [16384,512] (ws), Wo fp32 [512,512], out fp32 row-major (d_out).
// ---------------------------------------------------------------------------
__global__ __launch_bounds__(256, 2) void proj_out_mfma(
    const unsigned short* __restrict__ Xb,
    const float* __restrict__ W,
    const float* __restrict__ bias,
    float* __restrict__ out)
{
    __shared__ __align__(16) unsigned short Xs[128][72];
    __shared__ __align__(16) unsigned short Ws[128][72];
    const int t = threadIdx.x;
    const int w = t >> 6, l = t & 63;
    const int l15 = l & 15, lg = l >> 4;
    const int n0 = blockIdx.x * 128, m0 = blockIdx.y * 128;
    const int mo = (w & 1) * 64, no = (w >> 1) * 64;

    f32x4 acc[4][4];
#pragma unroll
    for (int i = 0; i < 4; i++)
#pragma unroll
        for (int j = 0; j < 4; j++) acc[i][j] = (f32x4){0.f, 0.f, 0.f, 0.f};

    for (int k0 = 0; k0 < DM; k0 += 64) {
        __syncthreads();
#pragma unroll
        for (int rr = 0; rr < 4; rr++) {
            int idx = rr * 2048 + t * 8;
            int row = idx >> 6, col = idx & 63;
            *(uint4*)&Xs[row][col] = *(const uint4*)(Xb + (size_t)(m0 + row) * DM + k0 + col);
            *(uint4*)&Ws[row][col] = cvt8(W + (size_t)(n0 + row) * DM + k0 + col);
        }
        __syncthreads();

        bf16x8 af[4][2], bfr[4][2];
#pragma unroll
        for (int mt = 0; mt < 4; mt++) {
            af[mt][0] = *(const bf16x8*)&Xs[mo + mt * 16 + l15][lg * 8];
            af[mt][1] = *(const bf16x8*)&Xs[mo + mt * 16 + l15][32 + lg * 8];
        }
#pragma unroll
        for (int nt = 0; nt < 4; nt++) {
            bfr[nt][0] = *(const bf16x8*)&Ws[no + nt * 16 + l15][lg * 8];
            bfr[nt][1] = *(const bf16x8*)&Ws[no + nt * 16 + l15][32 + lg * 8];
        }
#pragma unroll
        for (int mt = 0; mt < 4; mt++)
#pragma unroll
            for (int nt = 0; nt < 4; nt++) {
                acc[mt][nt] = MFMA16(af[mt][0], bfr[nt][0], acc[mt][nt]);
                acc[mt][nt] = MFMA16(af[mt][1], bfr[nt][1], acc[mt][nt]);
            }
    }

    float bv4[4];
#pragma unroll
    for (int nt = 0; nt < 4; nt++) bv4[nt] = bias[n0 + no + nt * 16 + l15];

#pragma unroll
    for (int mt = 0; mt < 4; mt++)
#pragma unroll
        for (int nt = 0; nt < 4; nt++)
#pragma unroll
            for (int r = 0; r < 4; r++) {
                int m = m0 + mo + mt * 16 + lg * 4 + r;
                int n = n0 + no + nt * 16 + l15;
                out[(size_t)m * DM + n] = acc[mt][nt][r] + bv4[nt];
            }
}

// ---------------------------------------------------------------------------
// Flash attention, bf16 MFMA — EXACT round-7 structure (best measured:
// ~147 µs). Block = (qblock of 256 rows) x (b,h), 512 thr, 8 waves; wave w
// owns q rows [w*32, w*32+32) (NQT=2). kv tiles of 64, simple 2-barrier
// staging (1 uint4/thread/buffer). Round-8 reg-prefetch spilled (VGPR pin
// 64); round-9 gll16-dbuf was −5% despite fewer conflicts -> staging is NOT
// the critical path; keep the simple proven form.
// S^T = K·Q^T; softmax exp2-domain; bit-packed mask; defer-max (THR=0).
// l via ones-column MFMA (Osum = P·1). Pw swizzled, wave-private.
// ---------------------------------------------------------------------------
__global__ __launch_bounds__(512, 4) void attn_kernel(
    const unsigned short* __restrict__ qw, const unsigned short* __restrict__ kw,
    const unsigned short* __restrict__ vtw,
    const unsigned long long* __restrict__ mb,
    unsigned short* __restrict__ ao)   // [B,S,512] bf16
{
    __shared__ __align__(16) unsigned short Ks[64][72];   // [kv][d]
    __shared__ __align__(16) unsigned short Vt[64][72];   // [d][kv]
    __shared__ __align__(16) unsigned short Pw[8 * 32 * 64]; // per-wave [q][kv] swizzled
    const int t = threadIdx.x;
    const int w = t >> 6, l = t & 63;
    const int l15 = l & 15, lg = l >> 4;
    const int q0 = blockIdx.x * 256;
    const int bh = blockIdx.y;
    const int b = bh >> 3, h = bh & 7;
    const int q0w = q0 + w * 32;
    const unsigned short* qb = qw + (size_t)bh * SS * DKK;
    const unsigned short* kb = kw + (size_t)bh * SS * DKK;
    const unsigned short* vtb = vtw + (size_t)bh * DKK * SS;

    // Per-qt bit-mask row base (row = q0w + qt*16 + l15; 32 words per row)
    const unsigned long long* mbq[2];
#pragma unroll
    for (int qt = 0; qt < 2; qt++)
        mbq[qt] = mb + ((size_t)(q0w + qt * 16 + l15) << 5);

    // Q fragments (B-operand): Qf[qt][dh] = Q[q0w+qt*16+l15][dh*32+lg*8 ..+8]
    bf16x8 Qf[2][2];
#pragma unroll
    for (int qt = 0; qt < 2; qt++)
#pragma unroll
        for (int dh = 0; dh < 2; dh++)
            Qf[qt][dh] = *(const bf16x8*)(qb + (size_t)(q0w + qt * 16 + l15) * DKK + dh * 32 + lg * 8);

    f32x4 O[2][4];    // [qt][dt]: row q = qt*16+lg*4+r, col d = dt*16+l15
    f32x4 Osum[2];    // ones-column accumulator: row sums of P (l denominator)
#pragma unroll
    for (int i = 0; i < 2; i++) {
#pragma unroll
        for (int j = 0; j < 4; j++) O[i][j] = (f32x4){0.f, 0.f, 0.f, 0.f};
        Osum[i] = (f32x4){0.f, 0.f, 0.f, 0.f};
    }
    float m_i[2];
#pragma unroll
    for (int i = 0; i < 2; i++) m_i[i] = -INFINITY;

    const bf16x8 vone = {16256, 16256, 16256, 16256, 16256, 16256, 16256, 16256}; // bf16 1.0 x8
    const int pbase = w * 2048;

    for (int kv0 = 0; kv0 < SS; kv0 += 64) {
        __syncthreads();   // all waves done with Ks/Vt of previous tile
        // ---- stage K tile + (pre-transposed) V tile: 1 uint4/thread each ----
        {
            int idx = t * 8;                 // 512 threads x 8 shorts = 64x64
            int row = idx >> 6, col = idx & 63;
            *(uint4*)&Ks[row][col] = *(const uint4*)(kb + (size_t)(kv0 + row) * DKK + col);
            *(uint4*)&Vt[row][col] = *(const uint4*)(vtb + (size_t)row * SS + kv0 + col);
        }
        __syncthreads();

        // ---- S^T = K·Q^T : S[kvt][qt], row kv = kvt*16+lg*4+r, col q = qt*16+l15
        f32x4 S[4][2];
#pragma unroll
        for (int kvt = 0; kvt < 4; kvt++) {
            bf16x8 ak0 = *(const bf16x8*)&Ks[kvt * 16 + l15][lg * 8];
            bf16x8 ak1 = *(const bf16x8*)&Ks[kvt * 16 + l15][32 + lg * 8];
#pragma unroll
            for (int qt = 0; qt < 2; qt++) {
                f32x4 z = (f32x4){0.f, 0.f, 0.f, 0.f};
                z = MFMA16(ak0, Qf[qt][0], z);
                z = MFMA16(ak1, Qf[qt][1], z);
                S[kvt][qt] = z;
            }
        }

        // ---- mask via packed bits: bit kv_local = kvt*16 + lg*4 + r ----
#pragma unroll
        for (int qt = 0; qt < 2; qt++) {
            unsigned long long mm = mbq[qt][kv0 >> 6];
            unsigned int wlo = (unsigned int)mm;
            unsigned int whi = (unsigned int)(mm >> 32);
            unsigned int u[4];
            u[0] = wlo >> (lg * 4);
            u[1] = wlo >> (16 + lg * 4);
            u[2] = whi >> (lg * 4);
            u[3] = whi >> (16 + lg * 4);
#pragma unroll
            for (int kvt = 0; kvt < 4; kvt++) {
                if (!(u[kvt] & 1u)) S[kvt][qt][0] = -1e38f;
                if (!(u[kvt] & 2u)) S[kvt][qt][1] = -1e38f;
                if (!(u[kvt] & 4u)) S[kvt][qt][2] = -1e38f;
                if (!(u[kvt] & 8u)) S[kvt][qt][3] = -1e38f;
            }
        }

        // ---- online softmax (exp2 domain) with defer-max (THR=0) ----
        float mtl[2];
#pragma unroll
        for (int qt = 0; qt < 2; qt++) {
            // balanced max3 tree over the 16 values (v_max3_f32 fusion)
            float mt = fmaxf(
                max3f(max3f(S[0][qt][0], S[0][qt][1], S[0][qt][2]),
                      max3f(S[0][qt][3], S[1][qt][0], S[1][qt][1]),
                      max3f(S[1][qt][2], S[1][qt][3], S[2][qt][0])),
                fmaxf(max3f(S[2][qt][1], S[2][qt][2], S[2][qt][3]),
                      max3f(S[3][qt][0], S[3][qt][1], fmaxf(S[3][qt][2], S[3][qt][3]))));
            mt = fmaxf(mt, __shfl_xor(mt, 16));
            mt = fmaxf(mt, __shfl_xor(mt, 32));
            mtl[qt] = mt;
        }
        int grow = (mtl[0] > m_i[0]) | (mtl[1] > m_i[1]);
        if (__any(grow)) {
            float alpha[2];
#pragma unroll
            for (int qt = 0; qt < 2; qt++) {
                float mn = fmaxf(m_i[qt], mtl[qt]);
                alpha[qt] = EXP2(m_i[qt] - mn);
                m_i[qt] = mn;
            }
            // rescale O and Osum by alpha (broadcast from q-col lanes to q-row regs)
#pragma unroll
            for (int qt = 0; qt < 2; qt++)
#pragma unroll
                for (int r = 0; r < 4; r++) {
                    float a = __shfl(alpha[qt], lg * 4 + r);
#pragma unroll
                    for (int dt = 0; dt < 4; dt++) O[qt][dt][r] *= a;
                    Osum[qt][r] *= a;
                }
        }

#pragma unroll
        for (int qt = 0; qt < 2; qt++) {
            const int prow = qt * 16 + l15;
            const int swz = (prow & 7) << 3;
#pragma unroll
            for (int kvt = 0; kvt < 4; kvt++) {
                float p0 = EXP2(S[kvt][qt][0] - m_i[qt]);
                float p1 = EXP2(S[kvt][qt][1] - m_i[qt]);
                float p2 = EXP2(S[kvt][qt][2] - m_i[qt]);
                float p3 = EXP2(S[kvt][qt][3] - m_i[qt]);
                bf16x4 pk;
                pk[0] = (short)f2bf(p0); pk[1] = (short)f2bf(p1);
                pk[2] = (short)f2bf(p2); pk[3] = (short)f2bf(p3);
                *(bf16x4*)&Pw[pbase + prow * 64 + ((kvt * 16 + lg * 4) ^ swz)] = pk;
            }
        }

        // Pw is wave-private: per-wave DS ops complete in order, so a block
        // barrier is unnecessary. The fence stops the compiler from hoisting
        // the ap reads above the pk stores.
        asm volatile("s_waitcnt lgkmcnt(0)" ::: "memory");

        // ---- O += P·V ; Osum += P·1 (row sums == softmax denominator) ----
        bf16x8 bv2[4][2];
#pragma unroll
        for (int dt = 0; dt < 4; dt++) {
            bv2[dt][0] = *(const bf16x8*)&Vt[dt * 16 + l15][lg * 8];
            bv2[dt][1] = *(const bf16x8*)&Vt[dt * 16 + l15][32 + lg * 8];
        }
#pragma unroll
        for (int qt = 0; qt < 2; qt++) {
            const int prow = qt * 16 + l15;
            const int swz = (prow & 7) << 3;
            bf16x8 ap0 = *(const bf16x8*)&Pw[pbase + prow * 64 + ((lg * 8) ^ swz)];
            bf16x8 ap1 = *(const bf16x8*)&Pw[pbase + prow * 64 + ((32 + lg * 8) ^ swz)];
#pragma unroll
            for (int dt = 0; dt < 4; dt++) {
                O[qt][dt] = MFMA16(ap0, bv2[dt][0], O[qt][dt]);
                O[qt][dt] = MFMA16(ap1, bv2[dt][1], O[qt][dt]);
            }
            Osum[qt] = MFMA16(ap0, vone, Osum[qt]);
            Osum[qt] = MFMA16(ap1, vone, Osum[qt]);
        }
    }

    // ---- epilogue: normalize by Osum (per-lane, no shfl), store bf16 ----
#pragma unroll
    for (int qt = 0; qt < 2; qt++) {
#pragma unroll
        for (int r = 0; r < 4; r++) {
            float lv = 1.f / Osum[qt][r];
            int q = q0w + qt * 16 + lg * 4 + r;
            size_t base = ((size_t)b * SS + q) * DM + h * 64;
#pragma unroll
            for (int dt = 0; dt < 4; dt++)
                ao[base + dt * 16 + l15] = f2bf(O[qt][dt][r] * lv);
        }
    }
}

extern "C" void kernel_launch(void* const* d_in, const int* in_sizes, int n_in,
                              void* d_out, int out_size, void* d_ws, size_t ws_size,
                              hipStream_t stream) {
    // All float tensors are fp32 (proven). mask is int32.
    const float* Q    = (const float*)d_in[0];
    const float* K    = (const float*)d_in[1];
    const float* V    = (const float*)d_in[2];
    const int*   mask = (const int*)d_in[3];
    const float* Wq   = (const float*)d_in[4];
    const float* bq   = (const float*)d_in[5];
    const float* Wk   = (const float*)d_in[6];
    const float* bk   = (const float*)d_in[7];
    const float* Wv   = (const float*)d_in[8];
    const float* bv   = (const float*)d_in[9];
    const float* Wo   = (const float*)d_in[10];
    const float* bo   = (const float*)d_in[11];

    // ws: [qb 16 MB][kb 16 MB][vtb 16 MB][ab 16 MB] = 64 MB (proven-safe).
    // Scratch lifetimes (all stream-ordered):
    //   vtb: prep writes Xq-bf16 -> projQ reads it -> projKV(z=1) overwrites
    //        with V^T -> attn reads V^T.
    //   ab:  prep writes Xv-bf16 -> projKV(z=1) reads it -> attn overwrites
    //        with its output -> proj_out reads.
    //   d_out head: wb (bf16 Wq/Wk/Wv, 1.5 MB) — safe under BOTH
    //        bytes/elements interpretations of out_size (mask tail is at
    //        out_size-0.5MB >= 7.86 MB byte offset; wb is [0,1.5 MB)).
    const size_t SEG = (size_t)BB * HH * SS * DKK;  // 8,388,608 bf16 elems
    unsigned short* qb  = (unsigned short*)d_ws;
    unsigned short* kb  = qb + SEG;
    unsigned short* vtb = kb + SEG;
    unsigned short* ab  = vtb + SEG;

    unsigned short* wb = (unsigned short*)d_out;    // 3 x 262144 bf16 = 1.5 MB
    const size_t MB_BYTES = (size_t)SS * (SS / 64) * sizeof(unsigned long long); // 524288
    unsigned long long* mbits =
        (unsigned long long*)((char*)d_out + (size_t)out_size - MB_BYTES);

    const float qscale = 0.125f * 1.44269504088896340736f;  // 1/sqrt(dk) * log2(e)

    // prep: mask(16384) + W cvt(384) + Xq cvt(4096 -> vtb) + Xv cvt(4096 -> ab)
    prep_kernel<<<dim3(24960), 256, 0, stream>>>(mask, mbits, Wq, Wk, Wv, wb,
                                                 Q, V, vtb, ab);

    // Q projection first: reads Xq-bf16 from vtb before V overwrites it.
    proj_qkv<<<dim3(DM / 128, (BB * SS) / 128, 1), 256, 0, stream>>>(
        vtb, K, ab, wb, bq, bk, bv, qb, kb, vtb, qscale, 0);
    // K (fp32 cvt8 path) + V (bf16, transposed out) — disjoint in/out, one launch.
    proj_qkv<<<dim3(DM / 128, (BB * SS) / 128, 2), 256, 0, stream>>>(
        vtb, K, ab, wb, bq, bk, bv, qb, kb, vtb, qscale, 1);

    attn_kernel<<<dim3(SS / 256, BB * HH), 512, 0, stream>>>(qb, kb, vtb, mbits, ab);

    proj_out_mfma<<<dim3(DM / 128, (BB * SS) / 128), 256, 0, stream>>>(ab, Wo, bo, (float*)d_out);
}

// Round 12
// 372.956 us; speedup vs baseline: 1.0952x; 1.0952x over previous
//
#include <hip/hip_runtime.h>
#include <hip/hip_bf16.h>
#include <math.h>

#define BB 8
#define SS 2048
#define HH 8
#define DKK 64
#define DM 512

typedef short bf16x8 __attribute__((ext_vector_type(8)));
typedef short bf16x4 __attribute__((ext_vector_type(4)));
typedef float f32x4 __attribute__((ext_vector_type(4)));
#define MFMA16(a, b, c) __builtin_amdgcn_mfma_f32_16x16x32_bf16(a, b, c, 0, 0, 0)

#if __has_builtin(__builtin_amdgcn_exp2f)
#define EXP2(x) __builtin_amdgcn_exp2f(x)
#else
#define EXP2(x) exp2f(x)
#endif

__device__ __forceinline__ unsigned short f2bf(float f) {
    __hip_bfloat16 h = __float2bfloat16(f);
    return *reinterpret_cast<unsigned short*>(&h);
}

__device__ __forceinline__ float max3f(float a, float b, float c) {
    return fmaxf(fmaxf(a, b), c);   // clang fuses to v_max3_f32
}

// Convert 8 consecutive fp32 -> 8 bf16, return as uint4 for a 16B store.
__device__ __forceinline__ uint4 cvt8(const float* __restrict__ src) {
    float4 a = *(const float4*)src;
    float4 b = *(const float4*)(src + 4);
    unsigned short tmp[8];
    tmp[0] = f2bf(a.x); tmp[1] = f2bf(a.y); tmp[2] = f2bf(a.z); tmp[3] = f2bf(a.w);
    tmp[4] = f2bf(b.x); tmp[5] = f2bf(b.y); tmp[6] = f2bf(b.z); tmp[7] = f2bf(b.w);
    return *(uint4*)tmp;
}

// ---------------------------------------------------------------------------
// Mask bit-pack: mask int32 [S][S] -> mb uint64 [S][S/64], bit i of word
// (q, c) = (mask[q][c*64+i] != 0). One wave per output word via __ballot.
// ---------------------------------------------------------------------------
__global__ __launch_bounds__(256) void mask_pack(
    const int* __restrict__ mask, unsigned long long* __restrict__ mb)
{
    const int t = threadIdx.x;
    const int wid = (blockIdx.x << 2) | (t >> 6);   // global wave id == word idx
    const int lane = t & 63;
    const int q = wid >> 5;          // / (SS/64)
    const int c = wid & 31;
    int e = mask[(size_t)q * SS + (c << 6) + lane];
    unsigned long long bal = __ballot(e != 0);
    if (lane == 0) mb[wid] = bal;
}

// ---------------------------------------------------------------------------
// W pre-convert: Wq/Wk/Wv fp32 [512][512] -> bf16, same layout, packed into
// dst (3 x 262144 elems = 1.5 MB).
// ---------------------------------------------------------------------------
__global__ __launch_bounds__(256) void w_cvt(
    const float* __restrict__ Wq, const float* __restrict__ Wk,
    const float* __restrict__ Wv, unsigned short* __restrict__ dst)
{
    const int idx = blockIdx.x * 256 + threadIdx.x;   // 0..98303
    const int which = idx >> 15;                       // / 32768
    const int off = (idx & 32767) * 8;
    const float* src = (which == 0) ? Wq : (which == 1) ? Wk : Wv;
    *(uint4*)(dst + (size_t)which * 262144 + off) = cvt8(src + off);
}

// ---------------------------------------------------------------------------
// Wo pre-convert (launched AFTER attn; writes into the then-dead qb segment
// — the only scratch alive at proj_out time, since proj_out overwrites all
// of d_out). Removes proj_out's 128x-redundant cvt8 of Wo.
// ---------------------------------------------------------------------------
__global__ __launch_bounds__(256) void wo_cvt(
    const float* __restrict__ Wo, unsigned short* __restrict__ dst)
{
    const size_t off = ((size_t)blockIdx.x * 256 + threadIdx.x) * 8;  // 128 blocks
    *(uint4*)(dst + off) = cvt8(Wo + off);
}

// ---------------------------------------------------------------------------
// Fused QKV projection (gridDim.z selects Q/K/V) — round-7 proven form.
// out[m][n] = (sum_k X[m][k]*W[n][k] + bias[n]) * scale. W pre-converted
// bf16 (uint4-copy staging); X fp32 (cvt8 staging).
// z=0 (Q), z=1 (K): out bf16 scattered to [B*H][S][64] (n = h*64+d).
// z=2 (V): out written TRANSPOSED to [B*H][64][S].
// ---------------------------------------------------------------------------
__global__ __launch_bounds__(256, 2) void proj_qkv_fused(
    const float* __restrict__ Xq, const float* __restrict__ Xk, const float* __restrict__ Xv,
    const unsigned short* __restrict__ Wb,
    const float* __restrict__ bq, const float* __restrict__ bk, const float* __restrict__ bv,
    unsigned short* __restrict__ outbase, float qscale)
{
    const int z = blockIdx.z;
    const float* X = (z == 0) ? Xq : (z == 1) ? Xk : Xv;
    const unsigned short* W = Wb + (size_t)z * 262144;
    const float* bias = (z == 0) ? bq : (z == 1) ? bk : bv;
    unsigned short* out = outbase + (size_t)z * ((size_t)BB * HH * SS * DKK);
    const float scale = (z == 0) ? qscale : 1.0f;

    __shared__ __align__(16) unsigned short Xs[128][72];
    __shared__ __align__(16) unsigned short Ws[128][72];
    const int t = threadIdx.x;
    const int w = t >> 6, l = t & 63;
    const int l15 = l & 15, lg = l >> 4;
    const int n0 = blockIdx.x * 128, m0 = blockIdx.y * 128;
    const int mo = (w & 1) * 64, no = (w >> 1) * 64;

    f32x4 acc[4][4];
#pragma unroll
    for (int i = 0; i < 4; i++)
#pragma unroll
        for (int j = 0; j < 4; j++) acc[i][j] = (f32x4){0.f, 0.f, 0.f, 0.f};

    for (int k0 = 0; k0 < DM; k0 += 64) {
        __syncthreads();
#pragma unroll
        for (int rr = 0; rr < 4; rr++) {
            int idx = rr * 2048 + t * 8;
            int row = idx >> 6, col = idx & 63;
            *(uint4*)&Xs[row][col] = cvt8(X + (size_t)(m0 + row) * DM + k0 + col);
            *(uint4*)&Ws[row][col] = *(const uint4*)(W + (size_t)(n0 + row) * DM + k0 + col);
        }
        __syncthreads();

        bf16x8 af[4][2], bfr[4][2];
#pragma unroll
        for (int mt = 0; mt < 4; mt++) {
            af[mt][0] = *(const bf16x8*)&Xs[mo + mt * 16 + l15][lg * 8];
            af[mt][1] = *(const bf16x8*)&Xs[mo + mt * 16 + l15][32 + lg * 8];
        }
#pragma unroll
        for (int nt = 0; nt < 4; nt++) {
            bfr[nt][0] = *(const bf16x8*)&Ws[no + nt * 16 + l15][lg * 8];
            bfr[nt][1] = *(const bf16x8*)&Ws[no + nt * 16 + l15][32 + lg * 8];
        }
#pragma unroll
        for (int mt = 0; mt < 4; mt++)
#pragma unroll
            for (int nt = 0; nt < 4; nt++) {
                acc[mt][nt] = MFMA16(af[mt][0], bfr[nt][0], acc[mt][nt]);
                acc[mt][nt] = MFMA16(af[mt][1], bfr[nt][1], acc[mt][nt]);
            }
    }

    float bv4[4];
#pragma unroll
    for (int nt = 0; nt < 4; nt++) bv4[nt] = bias[n0 + no + nt * 16 + l15];

    const int h = (n0 + no) >> 6;
    if (z == 2) {
        // transposed V epilogue: vt[bh][d][s]
#pragma unroll
        for (int mt = 0; mt < 4; mt++) {
            int m = m0 + mo + mt * 16 + lg * 4;       // 4-aligned, never crosses b
            int bb = m >> 11, s = m & (SS - 1);
#pragma unroll
            for (int nt = 0; nt < 4; nt++) {
                int d = nt * 16 + l15;
                bf16x4 pk;
#pragma unroll
                for (int r = 0; r < 4; r++) pk[r] = (short)f2bf(acc[mt][nt][r] + bv4[nt]);
                *(bf16x4*)(out + (((size_t)bb * HH + h) * DKK + d) * SS + s) = pk;
            }
        }
    } else {
#pragma unroll
        for (int mt = 0; mt < 4; mt++)
#pragma unroll
            for (int nt = 0; nt < 4; nt++)
#pragma unroll
                for (int r = 0; r < 4; r++) {
                    int m = m0 + mo + mt * 16 + lg * 4 + r;
                    int d = nt * 16 + l15;
                    float v = (acc[mt][nt][r] + bv4[nt]) * scale;
                    int bb = m >> 11, s = m & (SS - 1);
                    out[(((size_t)bb * HH + h) * SS + s) * 64 + d] = f2bf(v);
                }
    }
}

// ---------------------------------------------------------------------------
// Output projection: out[m][n] = sum_k A[m][k]*Wo[n][k] + bo[n]
// A bf16 [16384,512] (ws), Wo PRE-CONVERTED bf16 (uint4 staging — removes
// the 128x-redundant cvt8), out fp32 row-major (d_out).
// ---------------------------------------------------------------------------
__global__ __launch_bounds__(256, 2) void proj_out_mfma(
    const unsigned short* __restrict__ Xb,
    const unsigned short* __restrict__ W,
    const float* __restrict__ bias,
    float* __restrict__ out)
{
    __shared__ __align__(16) unsigned short Xs[128][72];
    __shared__ __align__(16) unsigned short Ws[128][72];
    const int t = threadIdx.x;
    const int w = t >> 6, l = t & 63;
    const int l15 = l & 15, lg = l >> 4;
    const int n0 = blockIdx.x * 128, m0 = blockIdx.y * 128;
    const int mo = (w & 1) * 64, no = (w >> 1) * 64;

    f32x4 acc[4][4];
#pragma unroll
    for (int i = 0; i < 4; i++)
#pragma unroll
        for (int j = 0; j < 4; j++) acc[i][j] = (f32x4){0.f, 0.f, 0.f, 0.f};

    for (int k0 = 0; k0 < DM; k0 += 64) {
        __syncthreads();
#pragma unroll
        for (int rr = 0; rr < 4; rr++) {
            int idx = rr * 2048 + t * 8;
            int row = idx >> 6, col = idx & 63;
            *(uint4*)&Xs[row][col] = *(const uint4*)(Xb + (size_t)(m0 + row) * DM + k0 + col);
            *(uint4*)&Ws[row][col] = *(const uint4*)(W + (size_t)(n0 + row) * DM + k0 + col);
        }
        __syncthreads();

        bf16x8 af[4][2], bfr[4][2];
#pragma unroll
        for (int mt = 0; mt < 4; mt++) {
            af[mt][0] = *(const bf16x8*)&Xs[mo + mt * 16 + l15][lg * 8];
            af[mt][1] = *(const bf16x8*)&Xs[mo + mt * 16 + l15][32 + lg * 8];
        }
#pragma unroll
        for (int nt = 0; nt < 4; nt++) {
            bfr[nt][0] = *(const bf16x8*)&Ws[no + nt * 16 + l15][lg * 8];
            bfr[nt][1] = *(const bf16x8*)&Ws[no + nt * 16 + l15][32 + lg * 8];
        }
#pragma unroll
        for (int mt = 0; mt < 4; mt++)
#pragma unroll
            for (int nt = 0; nt < 4; nt++) {
                acc[mt][nt] = MFMA16(af[mt][0], bfr[nt][0], acc[mt][nt]);
                acc[mt][nt] = MFMA16(af[mt][1], bfr[nt][1], acc[mt][nt]);
            }
    }

    float bv4[4];
#pragma unroll
    for (int nt = 0; nt < 4; nt++) bv4[nt] = bias[n0 + no + nt * 16 + l15];

#pragma unroll
    for (int mt = 0; mt < 4; mt++)
#pragma unroll
        for (int nt = 0; nt < 4; nt++)
#pragma unroll
            for (int r = 0; r < 4; r++) {
                int m = m0 + mo + mt * 16 + lg * 4 + r;
                int n = n0 + no + nt * 16 + l15;
                out[(size_t)m * DM + n] = acc[mt][nt][r] + bv4[nt];
            }
}

// ---------------------------------------------------------------------------
// Flash attention, bf16 MFMA — round-7 structure (best measured: ~146 µs)
// + T5 s_setprio(1) around the two MFMA clusters. Between barriers the 16
// waves/CU diverge across MFMA/VALU phases (defer-max branch), so priority
// arbitration has role diversity to exploit (m191 regime; m190's lockstep
// null doesn't apply mid-tile).
// Block = (qblock of 256 rows) x (b,h), 512 thr, 8 waves; wave w owns q rows
// [w*32, w*32+32) (NQT=2). kv tiles of 64, simple 2-barrier staging.
// S^T = K·Q^T; softmax exp2-domain; bit-packed mask; defer-max (THR=0).
// l via ones-column MFMA (Osum = P·1). Pw swizzled, wave-private.
// ---------------------------------------------------------------------------
__global__ __launch_bounds__(512, 4) void attn_kernel(
    const unsigned short* __restrict__ qw, const unsigned short* __restrict__ kw,
    const unsigned short* __restrict__ vtw,
    const unsigned long long* __restrict__ mb,
    unsigned short* __restrict__ ao)   // [B,S,512] bf16
{
    __shared__ __align__(16) unsigned short Ks[64][72];   // [kv][d]
    __shared__ __align__(16) unsigned short Vt[64][72];   // [d][kv]
    __shared__ __align__(16) unsigned short Pw[8 * 32 * 64]; // per-wave [q][kv] swizzled
    const int t = threadIdx.x;
    const int w = t >> 6, l = t & 63;
    const int l15 = l & 15, lg = l >> 4;
    const int q0 = blockIdx.x * 256;
    const int bh = blockIdx.y;
    const int b = bh >> 3, h = bh & 7;
    const int q0w = q0 + w * 32;
    const unsigned short* qb = qw + (size_t)bh * SS * DKK;
    const unsigned short* kb = kw + (size_t)bh * SS * DKK;
    const unsigned short* vtb = vtw + (size_t)bh * DKK * SS;

    // Per-qt bit-mask row base (row = q0w + qt*16 + l15; 32 words per row)
    const unsigned long long* mbq[2];
#pragma unroll
    for (int qt = 0; qt < 2; qt++)
        mbq[qt] = mb + ((size_t)(q0w + qt * 16 + l15) << 5);

    // Q fragments (B-operand): Qf[qt][dh] = Q[q0w+qt*16+l15][dh*32+lg*8 ..+8]
    bf16x8 Qf[2][2];
#pragma unroll
    for (int qt = 0; qt < 2; qt++)
#pragma unroll
        for (int dh = 0; dh < 2; dh++)
            Qf[qt][dh] = *(const bf16x8*)(qb + (size_t)(q0w + qt * 16 + l15) * DKK + dh * 32 + lg * 8);

    f32x4 O[2][4];    // [qt][dt]: row q = qt*16+lg*4+r, col d = dt*16+l15
    f32x4 Osum[2];    // ones-column accumulator: row sums of P (l denominator)
#pragma unroll
    for (int i = 0; i < 2; i++) {
#pragma unroll
        for (int j = 0; j < 4; j++) O[i][j] = (f32x4){0.f, 0.f, 0.f, 0.f};
        Osum[i] = (f32x4){0.f, 0.f, 0.f, 0.f};
    }
    float m_i[2];
#pragma unroll
    for (int i = 0; i < 2; i++) m_i[i] = -INFINITY;

    const bf16x8 vone = {16256, 16256, 16256, 16256, 16256, 16256, 16256, 16256}; // bf16 1.0 x8
    const int pbase = w * 2048;

    for (int kv0 = 0; kv0 < SS; kv0 += 64) {
        __syncthreads();   // all waves done with Ks/Vt of previous tile
        // ---- stage K tile + (pre-transposed) V tile: 1 uint4/thread each ----
        {
            int idx = t * 8;                 // 512 threads x 8 shorts = 64x64
            int row = idx >> 6, col = idx & 63;
            *(uint4*)&Ks[row][col] = *(const uint4*)(kb + (size_t)(kv0 + row) * DKK + col);
            *(uint4*)&Vt[row][col] = *(const uint4*)(vtb + (size_t)row * SS + kv0 + col);
        }
        __syncthreads();

        // ---- S^T = K·Q^T : S[kvt][qt], row kv = kvt*16+lg*4+r, col q = qt*16+l15
        f32x4 S[4][2];
        __builtin_amdgcn_s_setprio(1);
#pragma unroll
        for (int kvt = 0; kvt < 4; kvt++) {
            bf16x8 ak0 = *(const bf16x8*)&Ks[kvt * 16 + l15][lg * 8];
            bf16x8 ak1 = *(const bf16x8*)&Ks[kvt * 16 + l15][32 + lg * 8];
#pragma unroll
            for (int qt = 0; qt < 2; qt++) {
                f32x4 z = (f32x4){0.f, 0.f, 0.f, 0.f};
                z = MFMA16(ak0, Qf[qt][0], z);
                z = MFMA16(ak1, Qf[qt][1], z);
                S[kvt][qt] = z;
            }
        }
        __builtin_amdgcn_s_setprio(0);

        // ---- mask via packed bits: bit kv_local = kvt*16 + lg*4 + r ----
#pragma unroll
        for (int qt = 0; qt < 2; qt++) {
            unsigned long long mm = mbq[qt][kv0 >> 6];
            unsigned int wlo = (unsigned int)mm;
            unsigned int whi = (unsigned int)(mm >> 32);
            unsigned int u[4];
            u[0] = wlo >> (lg * 4);
            u[1] = wlo >> (16 + lg * 4);
            u[2] = whi >> (lg * 4);
            u[3] = whi >> (16 + lg * 4);
#pragma unroll
            for (int kvt = 0; kvt < 4; kvt++) {
                if (!(u[kvt] & 1u)) S[kvt][qt][0] = -1e38f;
                if (!(u[kvt] & 2u)) S[kvt][qt][1] = -1e38f;
                if (!(u[kvt] & 4u)) S[kvt][qt][2] = -1e38f;
                if (!(u[kvt] & 8u)) S[kvt][qt][3] = -1e38f;
            }
        }

        // ---- online softmax (exp2 domain) with defer-max (THR=0) ----
        float mtl[2];
#pragma unroll
        for (int qt = 0; qt < 2; qt++) {
            // balanced max3 tree over the 16 values (v_max3_f32 fusion)
            float mt = fmaxf(
                max3f(max3f(S[0][qt][0], S[0][qt][1], S[0][qt][2]),
                      max3f(S[0][qt][3], S[1][qt][0], S[1][qt][1]),
                      max3f(S[1][qt][2], S[1][qt][3], S[2][qt][0])),
                fmaxf(max3f(S[2][qt][1], S[2][qt][2], S[2][qt][3]),
                      max3f(S[3][qt][0], S[3][qt][1], fmaxf(S[3][qt][2], S[3][qt][3]))));
            mt = fmaxf(mt, __shfl_xor(mt, 16));
            mt = fmaxf(mt, __shfl_xor(mt, 32));
            mtl[qt] = mt;
        }
        int grow = (mtl[0] > m_i[0]) | (mtl[1] > m_i[1]);
        if (__any(grow)) {
            float alpha[2];
#pragma unroll
            for (int qt = 0; qt < 2; qt++) {
                float mn = fmaxf(m_i[qt], mtl[qt]);
                alpha[qt] = EXP2(m_i[qt] - mn);
                m_i[qt] = mn;
            }
            // rescale O and Osum by alpha (broadcast from q-col lanes to q-row regs)
#pragma unroll
            for (int qt = 0; qt < 2; qt++)
#pragma unroll
                for (int r = 0; r < 4; r++) {
                    float a = __shfl(alpha[qt], lg * 4 + r);
#pragma unroll
                    for (int dt = 0; dt < 4; dt++) O[qt][dt][r] *= a;
                    Osum[qt][r] *= a;
                }
        }

#pragma unroll
        for (int qt = 0; qt < 2; qt++) {
            const int prow = qt * 16 + l15;
            const int swz = (prow & 7) << 3;
#pragma unroll
            for (int kvt = 0; kvt < 4; kvt++) {
                float p0 = EXP2(S[kvt][qt][0] - m_i[qt]);
                float p1 = EXP2(S[kvt][qt][1] - m_i[qt]);
                float p2 = EXP2(S[kvt][qt][2] - m_i[qt]);
                float p3 = EXP2(S[kvt][qt][3] - m_i[qt]);
                bf16x4 pk;
                pk[0] = (short)f2bf(p0); pk[1] = (short)f2bf(p1);
                pk[2] = (short)f2bf(p2); pk[3] = (short)f2bf(p3);
                *(bf16x4*)&Pw[pbase + prow * 64 + ((kvt * 16 + lg * 4) ^ swz)] = pk;
            }
        }

        // Pw is wave-private: per-wave DS ops complete in order, so a block
        // barrier is unnecessary. The fence stops the compiler from hoisting
        // the ap reads above the pk stores.
        asm volatile("s_waitcnt lgkmcnt(0)" ::: "memory");

        // ---- O += P·V ; Osum += P·1 (row sums == softmax denominator) ----
        bf16x8 bv2[4][2];
#pragma unroll
        for (int dt = 0; dt < 4; dt++) {
            bv2[dt][0] = *(const bf16x8*)&Vt[dt * 16 + l15][lg * 8];
            bv2[dt][1] = *(const bf16x8*)&Vt[dt * 16 + l15][32 + lg * 8];
        }
        __builtin_amdgcn_s_setprio(1);
#pragma unroll
        for (int qt = 0; qt < 2; qt++) {
            const int prow = qt * 16 + l15;
            const int swz = (prow & 7) << 3;
            bf16x8 ap0 = *(const bf16x8*)&Pw[pbase + prow * 64 + ((lg * 8) ^ swz)];
            bf16x8 ap1 = *(const bf16x8*)&Pw[pbase + prow * 64 + ((32 + lg * 8) ^ swz)];
#pragma unroll
            for (int dt = 0; dt < 4; dt++) {
                O[qt][dt] = MFMA16(ap0, bv2[dt][0], O[qt][dt]);
                O[qt][dt] = MFMA16(ap1, bv2[dt][1], O[qt][dt]);
            }
            Osum[qt] = MFMA16(ap0, vone, Osum[qt]);
            Osum[qt] = MFMA16(ap1, vone, Osum[qt]);
        }
        __builtin_amdgcn_s_setprio(0);
    }

    // ---- epilogue: normalize by Osum (per-lane, no shfl), store bf16 ----
#pragma unroll
    for (int qt = 0; qt < 2; qt++) {
#pragma unroll
        for (int r = 0; r < 4; r++) {
            float lv = 1.f / Osum[qt][r];
            int q = q0w + qt * 16 + lg * 4 + r;
            size_t base = ((size_t)b * SS + q) * DM + h * 64;
#pragma unroll
            for (int dt = 0; dt < 4; dt++)
                ao[base + dt * 16 + l15] = f2bf(O[qt][dt][r] * lv);
        }
    }
}

extern "C" void kernel_launch(void* const* d_in, const int* in_sizes, int n_in,
                              void* d_out, int out_size, void* d_ws, size_t ws_size,
                              hipStream_t stream) {
    // All float tensors are fp32 (proven). mask is int32.
    const float* Q    = (const float*)d_in[0];
    const float* K    = (const float*)d_in[1];
    const float* V    = (const float*)d_in[2];
    const int*   mask = (const int*)d_in[3];
    const float* Wq   = (const float*)d_in[4];
    const float* bq   = (const float*)d_in[5];
    const float* Wk   = (const float*)d_in[6];
    const float* bk   = (const float*)d_in[7];
    const float* Wv   = (const float*)d_in[8];
    const float* bv   = (const float*)d_in[9];
    const float* Wo   = (const float*)d_in[10];
    const float* bo   = (const float*)d_in[11];

    // ws: [qb 16 MB][kb 16 MB][vtb 16 MB][ab 16 MB] = 64 MB (proven-safe).
    // Scratch lifetimes (stream-ordered):
    //   ab head (wb, 1.5 MB): w_cvt writes Wq/Wk/Wv bf16 -> proj_qkv reads
    //        -> attn output overwrites.
    //   qb: proj writes Q -> attn reads -> DEAD -> wo_cvt writes Wo bf16
    //        (512 KB) -> proj_out reads. (d_out can't host Wo: proj_out
    //        overwrites all of d_out while reading W.)
    //   d_out tail: bit-packed mask (round-1-proven placement).
    const size_t SEG = (size_t)BB * HH * SS * DKK;  // 8,388,608 bf16 elems
    unsigned short* qb  = (unsigned short*)d_ws;
    unsigned short* kb  = qb + SEG;
    unsigned short* vtb = kb + SEG;
    unsigned short* ab  = vtb + SEG;
    unsigned short* wb  = ab;   // 3 x 262144 bf16 = 1.5 MB, dead before attn
    unsigned short* wob = qb;   // 262144 bf16 = 512 KB, written after attn

    const size_t MB_BYTES = (size_t)SS * (SS / 64) * sizeof(unsigned long long); // 524288
    unsigned long long* mbits =
        (unsigned long long*)((char*)d_out + (size_t)out_size - MB_BYTES);

    const float qscale = 0.125f * 1.44269504088896340736f;  // 1/sqrt(dk) * log2(e)

    mask_pack<<<dim3((SS * (SS / 64)) / 4), 256, 0, stream>>>(mask, mbits);
    w_cvt<<<dim3(384), 256, 0, stream>>>(Wq, Wk, Wv, wb);

    dim3 gp(DM / 128, (BB * SS) / 128, 3);  // (4, 128, 3)
    proj_qkv_fused<<<gp, 256, 0, stream>>>(Q, K, V, wb, bq, bk, bv, qb, qscale);

    attn_kernel<<<dim3(SS / 256, BB * HH), 512, 0, stream>>>(qb, kb, vtb, mbits, ab);

    wo_cvt<<<dim3(128), 256, 0, stream>>>(Wo, wob);

    proj_out_mfma<<<dim3(DM / 128, (BB * SS) / 128), 256, 0, stream>>>(ab, wob, bo, (float*)d_out);
}